// Round 2
// baseline (1004.858 us; speedup 1.0000x reference)
//
#include <hip/hip_runtime.h>
#include <cstdint>
#include <cstddef>

// Self-attention, DIM=4096, fp32 in/out — ZERO-workspace design.
//   q = x@Wq.T+bq ; k = x@Wk.T+bk ; v = x@Wv.T+bv   (bf16 MFMA, fp32 accum)
//   S = (q@k.T) / 64 ; P = softmax_row(S) ; out = P * v  (elementwise)
//
// Buffer plan (harness restores d_in from pristine copies before every timed
// launch, so consumed input buffers are legal scratch):
//   d_out lower half : xb  (x as bf16, 33.5 MB)
//   d_out upper half : wb  (current W as bf16, 33.5 MB; reused for Wq/Wk/Wv)
//   d_in[1] (Wq buf) : qb  (q as bf16)   — written after Wq consumed
//   d_in[3] (Wk buf) : kb  (k as bf16)   — written after Wk consumed
//   d_in[5] (Wv buf) : v   (fp32, 67 MB) — written after Wv consumed
//   d_out            : S (fp32) overwrites xb/wb, then softmax in-place.
//
// GEMM = verified m97 structure: 128x128 tile, BK=32, 4 waves (2x2 of 64x64),
// 4x4 of 16x16x32 bf16 MFMA per wave, global_load_lds width=16 staging.
//
// Verified fragment layouts (learn_hip m89/m91):
//   A frag:  A[m = lane&15][k = (lane>>4)*8 + j]   (8 bf16 / lane)
//   B frag (B^T input): B[n = lane&15][k = (lane>>4)*8 + j]
//   C/D:     col = lane&15, row = (lane>>4)*4 + reg

#define NDIM 4096

typedef __bf16 bf16x8 __attribute__((ext_vector_type(8)));
typedef float f32x4 __attribute__((ext_vector_type(4)));
typedef unsigned short us8 __attribute__((ext_vector_type(8)));

__device__ __forceinline__ unsigned short f2bf(float f) {
  unsigned int u = __float_as_uint(f);
  return (unsigned short)((u + 0x7fffu + ((u >> 16) & 1u)) >> 16);  // RNE
}

__device__ __forceinline__ void async_copy16(void* lds, const void* g) {
  __builtin_amdgcn_global_load_lds(
      (__attribute__((address_space(1))) void*)(uintptr_t)g,
      (__attribute__((address_space(3))) void*)lds,
      16, 0, 0);
}

__global__ __launch_bounds__(256) void cvt_f32_to_bf16(
    const float* __restrict__ src, unsigned short* __restrict__ dst) {
  const int i = blockIdx.x * 256 + threadIdx.x;  // 8 floats per thread
  const float4* s = (const float4*)src;
  float4 a = s[2 * i];
  float4 b = s[2 * i + 1];
  us8 o;
  o[0] = f2bf(a.x); o[1] = f2bf(a.y); o[2] = f2bf(a.z); o[3] = f2bf(a.w);
  o[4] = f2bf(b.x); o[5] = f2bf(b.y); o[6] = f2bf(b.z); o[7] = f2bf(b.w);
  ((us8*)dst)[i] = o;
}

__device__ __forceinline__ void store_out(float* p, float v) { *p = v; }
__device__ __forceinline__ void store_out(unsigned short* p, float v) { *p = f2bf(v); }

// C[m][n] = scale * sum_k A[m][k]*B[n][k] + bias[n]
template <typename OutT>
__global__ __launch_bounds__(256) void gemm_bt(
    const unsigned short* __restrict__ A,  // [4096][4096] bf16
    const unsigned short* __restrict__ B,  // [4096][4096] bf16 (row n = out col)
    OutT* __restrict__ C,                  // [4096][4096]
    const float* __restrict__ bias,        // [4096] or nullptr
    float scale) {
  __shared__ __align__(16) unsigned short As[128 * 32];  // [row][k] 8 KB
  __shared__ __align__(16) unsigned short Bs[128 * 32];

  const int t = threadIdx.x;
  const int bm = blockIdx.y, bn = blockIdx.x;
  const int wave = t >> 6, lane = t & 63;
  const int wm = wave >> 1, wn = wave & 1;   // 2x2 waves over 128x128
  const int quad = lane >> 4, l16 = lane & 15;

  // staging: thread t loads rows (t>>2) and (t>>2)+64, 16B chunk (t&3)
  const unsigned short* Ag = A + (size_t)(bm * 128 + (t >> 2)) * NDIM + (t & 3) * 8;
  const unsigned short* Bg = B + (size_t)(bn * 128 + (t >> 2)) * NDIM + (t & 3) * 8;
  unsigned short* As0 = &As[t * 8];  // byte offset t*16: [row=t>>2][chunk=t&3]
  unsigned short* Bs0 = &Bs[t * 8];

  const f32x4 zero = {0.f, 0.f, 0.f, 0.f};
  f32x4 acc[4][4];
#pragma unroll
  for (int i = 0; i < 4; ++i)
#pragma unroll
    for (int j = 0; j < 4; ++j) acc[i][j] = zero;

  for (int k0 = 0; k0 < NDIM; k0 += 32) {
    __syncthreads();  // previous iter's compute done before overwrite
    async_copy16(As0,        Ag + k0);
    async_copy16(As0 + 2048, Ag + (size_t)64 * NDIM + k0);  // +64 rows
    async_copy16(Bs0,        Bg + k0);
    async_copy16(Bs0 + 2048, Bg + (size_t)64 * NDIM + k0);
    __builtin_amdgcn_s_waitcnt(0);  // drain vmcnt: async loads landed in LDS
    __syncthreads();

    bf16x8 af[4], bfr[4];
#pragma unroll
    for (int i = 0; i < 4; ++i)
      af[i] = *(const bf16x8*)&As[(wm * 64 + i * 16 + l16) * 32 + quad * 8];
#pragma unroll
    for (int j = 0; j < 4; ++j)
      bfr[j] = *(const bf16x8*)&Bs[(wn * 64 + j * 16 + l16) * 32 + quad * 8];
#pragma unroll
    for (int i = 0; i < 4; ++i)
#pragma unroll
      for (int j = 0; j < 4; ++j)
        acc[i][j] = __builtin_amdgcn_mfma_f32_16x16x32_bf16(af[i], bfr[j],
                                                            acc[i][j], 0, 0, 0);
  }

#pragma unroll
  for (int j = 0; j < 4; ++j) {
    const int col = bn * 128 + wn * 64 + j * 16 + l16;
    const float bb = bias ? bias[col] : 0.0f;
#pragma unroll
    for (int i = 0; i < 4; ++i) {
      const int row0 = bm * 128 + wm * 64 + i * 16 + quad * 4;
#pragma unroll
      for (int r = 0; r < 4; ++r)
        store_out(C + (size_t)(row0 + r) * NDIM + col, acc[i][j][r] * scale + bb);
    }
  }
}

// one block per row: out[row][:] = softmax(S[row][:]) * V[row][:]
// S and out may alias (in-place): each thread reads its row elements into
// registers before any write.
__global__ __launch_bounds__(256) void softmax_mul(
    const float* __restrict__ S, const float* __restrict__ V,
    float* __restrict__ out) {
  const int row = blockIdx.x;
  const int t = threadIdx.x;
  const int lane = t & 63, wave = t >> 6;
  const float4* Sr = (const float4*)(S + (size_t)row * NDIM);
  const float4* Vr = (const float4*)(V + (size_t)row * NDIM);
  float4* Or = (float4*)(out + (size_t)row * NDIM);

  float4 p[4];
  float m = -3.4e38f;
#pragma unroll
  for (int c = 0; c < 4; ++c) {
    p[c] = Sr[t + 256 * c];
    m = fmaxf(m, fmaxf(fmaxf(p[c].x, p[c].y), fmaxf(p[c].z, p[c].w)));
  }
#pragma unroll
  for (int off = 32; off > 0; off >>= 1) m = fmaxf(m, __shfl_xor(m, off));
  __shared__ float redm[4], reds[4];
  if (lane == 0) redm[wave] = m;
  __syncthreads();
  m = fmaxf(fmaxf(redm[0], redm[1]), fmaxf(redm[2], redm[3]));

  float s = 0.f;
#pragma unroll
  for (int c = 0; c < 4; ++c) {
    p[c].x = __expf(p[c].x - m);
    p[c].y = __expf(p[c].y - m);
    p[c].z = __expf(p[c].z - m);
    p[c].w = __expf(p[c].w - m);
    s += (p[c].x + p[c].y) + (p[c].z + p[c].w);
  }
#pragma unroll
  for (int off = 32; off > 0; off >>= 1) s += __shfl_xor(s, off);
  if (lane == 0) reds[wave] = s;
  __syncthreads();
  s = (reds[0] + reds[1]) + (reds[2] + reds[3]);
  const float inv = 1.0f / s;

#pragma unroll
  for (int c = 0; c < 4; ++c) {
    float4 vv = Vr[t + 256 * c];
    float4 o;
    o.x = p[c].x * inv * vv.x;
    o.y = p[c].y * inv * vv.y;
    o.z = p[c].z * inv * vv.z;
    o.w = p[c].w * inv * vv.w;
    Or[t + 256 * c] = o;
  }
}

extern "C" void kernel_launch(void* const* d_in, const int* in_sizes, int n_in,
                              void* d_out, int out_size, void* d_ws, size_t ws_size,
                              hipStream_t stream) {
  const float* x  = (const float*)d_in[0];
  const float* Wq = (const float*)d_in[1];
  const float* bq = (const float*)d_in[2];
  const float* Wk = (const float*)d_in[3];
  const float* bk = (const float*)d_in[4];
  const float* Wv = (const float*)d_in[5];
  const float* bv = (const float*)d_in[6];
  float* out = (float*)d_out;

  const size_t NN = (size_t)NDIM * NDIM;

  // Scratch carved from d_out (67 MB = exactly 2 bf16 matrices) and from
  // consumed input buffers (restored by harness before every launch).
  unsigned short* xb = (unsigned short*)d_out;        // x  as bf16
  unsigned short* wb = xb + NN;                       // W* as bf16 (rotating)
  unsigned short* qb = (unsigned short*)d_in[1];      // q  as bf16 (in Wq buf)
  unsigned short* kb = (unsigned short*)d_in[3];      // k  as bf16 (in Wk buf)
  float*          vf = (float*)d_in[5];               // v  as fp32 (in Wv buf)
  float*          Sf = (float*)d_out;                 // S fp32 (after xb/wb dead)

  const int cvtBlocks = (int)(NN / (256 * 8));  // 8192
  dim3 gg(NDIM / 128, NDIM / 128);              // 32x32 blocks of 256 thr

  cvt_f32_to_bf16<<<cvtBlocks, 256, 0, stream>>>(x, xb);

  cvt_f32_to_bf16<<<cvtBlocks, 256, 0, stream>>>(Wq, wb);
  gemm_bt<unsigned short><<<gg, 256, 0, stream>>>(xb, wb, qb, bq, 1.0f);

  cvt_f32_to_bf16<<<cvtBlocks, 256, 0, stream>>>(Wk, wb);
  gemm_bt<unsigned short><<<gg, 256, 0, stream>>>(xb, wb, kb, bk, 1.0f);

  cvt_f32_to_bf16<<<cvtBlocks, 256, 0, stream>>>(Wv, wb);
  gemm_bt<float><<<gg, 256, 0, stream>>>(xb, wb, vf, bv, 1.0f);

  // S = q@k.T / 64 -> d_out (xb/wb no longer needed; stream-ordered)
  gemm_bt<float><<<gg, 256, 0, stream>>>(qb, kb, Sf, nullptr, 0.015625f);

  // out = softmax(S) * v, in-place on d_out
  softmax_mul<<<NDIM, 256, 0, stream>>>(Sf, vf, out);
}

// Round 3
// 978.789 us; speedup vs baseline: 1.0266x; 1.0266x over previous
//
#include <hip/hip_runtime.h>
#include <cstdint>
#include <cstddef>

// Self-attention, DIM=4096, fp32 in/out — zero-workspace design, round 3.
//
// Round-3 changes vs round 2 (1005 us):
//  * 3 projection GEMMs fused into ONE dispatch (grid.z=3, 3072 blocks).
//    3072 is an exact multiple of both 768 (3 blk/CU) and 1024 (4 blk/CU)
//    residency -> no 1-block/CU tail phase (round 2's 200us-per-GEMM vs
//    157us m97 plateau was exactly a 256-block tail at ~40% rate).
//  * S-GEMM gets __launch_bounds__(256,4): cap regs at 128/wave so 4
//    blocks/CU fit -> 1024-block grid divides evenly, tail gone.
//  * 4 converts -> 2 paired dispatches.
//
// Buffer plan (harness restores d_in before every launch; consumed input
// buffers are legal scratch):
//   cvt#1: x  -> d_out lo (xb),      Wq -> d_out hi (wqb)
//   cvt#2: Wk -> Wq-buf lo (wkb),    Wv -> Wq-buf hi (wvb)   [Wq consumed]
//   qkv  : reads xb + w*b; q -> Wk-buf lo (bf16), k -> Wk-buf hi (bf16),
//          v -> Wv-buf (fp32)                                 [Wk,Wv consumed]
//   S    : q@k.T/64 -> d_out (fp32; xb/wqb dead)
//   softmax*v in place on d_out.
//
// GEMM = verified m97 structure: 128x128 tile, BK=32, 4 waves (2x2 of 64x64),
// 4x4 of 16x16x32 bf16 MFMA per wave, global_load_lds width=16 staging.
// Fragment layouts per learn_hip m89/m91.

#define NDIM 4096

typedef __bf16 bf16x8 __attribute__((ext_vector_type(8)));
typedef float f32x4 __attribute__((ext_vector_type(4)));
typedef unsigned short us8 __attribute__((ext_vector_type(8)));

__device__ __forceinline__ unsigned short f2bf(float f) {
  unsigned int u = __float_as_uint(f);
  return (unsigned short)((u + 0x7fffu + ((u >> 16) & 1u)) >> 16);  // RNE
}

__device__ __forceinline__ void async_copy16(void* lds, const void* g) {
  __builtin_amdgcn_global_load_lds(
      (__attribute__((address_space(1))) void*)(uintptr_t)g,
      (__attribute__((address_space(3))) void*)lds,
      16, 0, 0);
}

// two fp32->bf16 converts in one dispatch (blockIdx.y picks the pair)
__global__ __launch_bounds__(256) void cvt2_f32_to_bf16(
    const float* __restrict__ s0, unsigned short* __restrict__ d0,
    const float* __restrict__ s1, unsigned short* __restrict__ d1) {
  const float* src = blockIdx.y ? s1 : s0;
  unsigned short* dst = blockIdx.y ? d1 : d0;
  const int i = blockIdx.x * 256 + threadIdx.x;  // 8 floats per thread
  const float4* s = (const float4*)src;
  float4 a = s[2 * i];
  float4 b = s[2 * i + 1];
  us8 o;
  o[0] = f2bf(a.x); o[1] = f2bf(a.y); o[2] = f2bf(a.z); o[3] = f2bf(a.w);
  o[4] = f2bf(b.x); o[5] = f2bf(b.y); o[6] = f2bf(b.z); o[7] = f2bf(b.w);
  ((us8*)dst)[i] = o;
}

// ---- shared GEMM core: computes acc[4][4] for one 128x128 tile ------------
__device__ __forceinline__ void gemm_core(
    const unsigned short* __restrict__ A, const unsigned short* __restrict__ B,
    int bm, int bn, int t, unsigned short* As, unsigned short* Bs,
    f32x4 acc[4][4]) {
  const int wave = t >> 6, lane = t & 63;
  const int wm = wave >> 1, wn = wave & 1;
  const int quad = lane >> 4, l16 = lane & 15;

  const unsigned short* Ag = A + (size_t)(bm * 128 + (t >> 2)) * NDIM + (t & 3) * 8;
  const unsigned short* Bg = B + (size_t)(bn * 128 + (t >> 2)) * NDIM + (t & 3) * 8;
  unsigned short* As0 = &As[t * 8];
  unsigned short* Bs0 = &Bs[t * 8];

  for (int k0 = 0; k0 < NDIM; k0 += 32) {
    __syncthreads();  // previous iter's compute done before overwrite
    async_copy16(As0,        Ag + k0);
    async_copy16(As0 + 2048, Ag + (size_t)64 * NDIM + k0);
    async_copy16(Bs0,        Bg + k0);
    async_copy16(Bs0 + 2048, Bg + (size_t)64 * NDIM + k0);
    __builtin_amdgcn_s_waitcnt(0);  // drain vmcnt: async loads landed in LDS
    __syncthreads();

    bf16x8 af[4], bfr[4];
#pragma unroll
    for (int i = 0; i < 4; ++i)
      af[i] = *(const bf16x8*)&As[(wm * 64 + i * 16 + l16) * 32 + quad * 8];
#pragma unroll
    for (int j = 0; j < 4; ++j)
      bfr[j] = *(const bf16x8*)&Bs[(wn * 64 + j * 16 + l16) * 32 + quad * 8];
#pragma unroll
    for (int i = 0; i < 4; ++i)
#pragma unroll
      for (int j = 0; j < 4; ++j)
        acc[i][j] = __builtin_amdgcn_mfma_f32_16x16x32_bf16(af[i], bfr[j],
                                                            acc[i][j], 0, 0, 0);
  }
}

// ---- fused q/k/v projection GEMM: grid (32,32,3) --------------------------
// z=0: q=x@Wq.T+bq -> bf16 ; z=1: k -> bf16 ; z=2: v -> fp32
__global__ __launch_bounds__(256) void gemm_qkv(
    const unsigned short* __restrict__ A,
    const unsigned short* __restrict__ B0,
    const unsigned short* __restrict__ B1,
    const unsigned short* __restrict__ B2,
    const float* __restrict__ bias0, const float* __restrict__ bias1,
    const float* __restrict__ bias2,
    unsigned short* __restrict__ qo, unsigned short* __restrict__ ko,
    float* __restrict__ vo) {
  __shared__ __align__(16) unsigned short As[128 * 32];
  __shared__ __align__(16) unsigned short Bs[128 * 32];

  const int t = threadIdx.x;
  const int bm = blockIdx.y, bn = blockIdx.x, z = blockIdx.z;
  const unsigned short* B = (z == 0) ? B0 : (z == 1) ? B1 : B2;
  const float* bias = (z == 0) ? bias0 : (z == 1) ? bias1 : bias2;

  const f32x4 zero = {0.f, 0.f, 0.f, 0.f};
  f32x4 acc[4][4];
#pragma unroll
  for (int i = 0; i < 4; ++i)
#pragma unroll
    for (int j = 0; j < 4; ++j) acc[i][j] = zero;

  gemm_core(A, B, bm, bn, t, As, Bs, acc);

  const int wave = t >> 6, lane = t & 63;
  const int wm = wave >> 1, wn = wave & 1;
  const int quad = lane >> 4, l16 = lane & 15;
#pragma unroll
  for (int j = 0; j < 4; ++j) {
    const int col = bn * 128 + wn * 64 + j * 16 + l16;
    const float bb = bias[col];
#pragma unroll
    for (int i = 0; i < 4; ++i) {
      const int row0 = bm * 128 + wm * 64 + i * 16 + quad * 4;
#pragma unroll
      for (int r = 0; r < 4; ++r) {
        const size_t idx = (size_t)(row0 + r) * NDIM + col;
        const float val = acc[i][j][r] + bb;
        if (z == 2)       vo[idx] = val;
        else if (z == 1)  ko[idx] = f2bf(val);
        else              qo[idx] = f2bf(val);
      }
    }
  }
}

// ---- S = scale * q@k.T (fp32 out), 4-blocks/CU via launch bounds ----------
__global__ __launch_bounds__(256, 4) void gemm_s(
    const unsigned short* __restrict__ A, const unsigned short* __restrict__ B,
    float* __restrict__ C, float scale) {
  __shared__ __align__(16) unsigned short As[128 * 32];
  __shared__ __align__(16) unsigned short Bs[128 * 32];

  const int t = threadIdx.x;
  const int bm = blockIdx.y, bn = blockIdx.x;

  const f32x4 zero = {0.f, 0.f, 0.f, 0.f};
  f32x4 acc[4][4];
#pragma unroll
  for (int i = 0; i < 4; ++i)
#pragma unroll
    for (int j = 0; j < 4; ++j) acc[i][j] = zero;

  gemm_core(A, B, bm, bn, t, As, Bs, acc);

  const int wave = t >> 6, lane = t & 63;
  const int wm = wave >> 1, wn = wave & 1;
  const int quad = lane >> 4, l16 = lane & 15;
#pragma unroll
  for (int j = 0; j < 4; ++j) {
    const int col = bn * 128 + wn * 64 + j * 16 + l16;
#pragma unroll
    for (int i = 0; i < 4; ++i) {
      const int row0 = bm * 128 + wm * 64 + i * 16 + quad * 4;
#pragma unroll
      for (int r = 0; r < 4; ++r)
        C[(size_t)(row0 + r) * NDIM + col] = acc[i][j][r] * scale;
    }
  }
}

// one block per row: out[row][:] = softmax(S[row][:]) * V[row][:]  (in-place ok)
__global__ __launch_bounds__(256) void softmax_mul(
    const float* __restrict__ S, const float* __restrict__ V,
    float* __restrict__ out) {
  const int row = blockIdx.x;
  const int t = threadIdx.x;
  const int lane = t & 63, wave = t >> 6;
  const float4* Sr = (const float4*)(S + (size_t)row * NDIM);
  const float4* Vr = (const float4*)(V + (size_t)row * NDIM);
  float4* Or = (float4*)(out + (size_t)row * NDIM);

  float4 p[4];
  float m = -3.4e38f;
#pragma unroll
  for (int c = 0; c < 4; ++c) {
    p[c] = Sr[t + 256 * c];
    m = fmaxf(m, fmaxf(fmaxf(p[c].x, p[c].y), fmaxf(p[c].z, p[c].w)));
  }
#pragma unroll
  for (int off = 32; off > 0; off >>= 1) m = fmaxf(m, __shfl_xor(m, off));
  __shared__ float redm[4], reds[4];
  if (lane == 0) redm[wave] = m;
  __syncthreads();
  m = fmaxf(fmaxf(redm[0], redm[1]), fmaxf(redm[2], redm[3]));

  float s = 0.f;
#pragma unroll
  for (int c = 0; c < 4; ++c) {
    p[c].x = __expf(p[c].x - m);
    p[c].y = __expf(p[c].y - m);
    p[c].z = __expf(p[c].z - m);
    p[c].w = __expf(p[c].w - m);
    s += (p[c].x + p[c].y) + (p[c].z + p[c].w);
  }
#pragma unroll
  for (int off = 32; off > 0; off >>= 1) s += __shfl_xor(s, off);
  if (lane == 0) reds[wave] = s;
  __syncthreads();
  s = (reds[0] + reds[1]) + (reds[2] + reds[3]);
  const float inv = 1.0f / s;

#pragma unroll
  for (int c = 0; c < 4; ++c) {
    float4 vv = Vr[t + 256 * c];
    float4 o;
    o.x = p[c].x * inv * vv.x;
    o.y = p[c].y * inv * vv.y;
    o.z = p[c].z * inv * vv.z;
    o.w = p[c].w * inv * vv.w;
    Or[t + 256 * c] = o;
  }
}

extern "C" void kernel_launch(void* const* d_in, const int* in_sizes, int n_in,
                              void* d_out, int out_size, void* d_ws, size_t ws_size,
                              hipStream_t stream) {
  const float* x  = (const float*)d_in[0];
  const float* Wq = (const float*)d_in[1];
  const float* bq = (const float*)d_in[2];
  const float* Wk = (const float*)d_in[3];
  const float* bk = (const float*)d_in[4];
  const float* Wv = (const float*)d_in[5];
  const float* bv = (const float*)d_in[6];
  float* out = (float*)d_out;

  const size_t NN = (size_t)NDIM * NDIM;

  unsigned short* xb  = (unsigned short*)d_out;   // x  bf16 (d_out lo)
  unsigned short* wqb = xb + NN;                  // Wq bf16 (d_out hi)
  unsigned short* wkb = (unsigned short*)d_in[1]; // Wk bf16 (Wq-buf lo)
  unsigned short* wvb = wkb + NN;                 // Wv bf16 (Wq-buf hi)
  unsigned short* qb  = (unsigned short*)d_in[3]; // q  bf16 (Wk-buf lo)
  unsigned short* kb  = qb + NN;                  // k  bf16 (Wk-buf hi)
  float*          vf  = (float*)d_in[5];          // v  fp32 (Wv-buf)
  float*          Sf  = (float*)d_out;            // S  fp32 (xb/wqb dead)

  const int cvtBlocks = (int)(NN / (256 * 8));    // 8192

  // cvt#1: x, Wq -> d_out halves (reads pristine x/Wq, writes d_out only)
  cvt2_f32_to_bf16<<<dim3(cvtBlocks, 2), 256, 0, stream>>>(x, xb, Wq, wqb);
  // cvt#2: Wk, Wv -> Wq-buf halves (Wq consumed by cvt#1)
  cvt2_f32_to_bf16<<<dim3(cvtBlocks, 2), 256, 0, stream>>>(Wk, wkb, Wv, wvb);

  // fused projections: 3072 blocks (tail-free at 3 or 4 blk/CU)
  gemm_qkv<<<dim3(32, 32, 3), 256, 0, stream>>>(xb, wqb, wkb, wvb,
                                                bq, bk, bv, qb, kb, vf);

  // S = q@k.T / 64 -> d_out
  gemm_s<<<dim3(32, 32), 256, 0, stream>>>(qb, kb, Sf, 0.015625f);

  // out = softmax(S) * v, in place on d_out
  softmax_mul<<<NDIM, 256, 0, stream>>>(Sf, vf, out);
}

// Round 4
// 885.713 us; speedup vs baseline: 1.1345x; 1.1051x over previous
//
#include <hip/hip_runtime.h>
#include <cstdint>
#include <cstddef>

// Self-attention, DIM=4096, fp32 in/out — zero-workspace, round 4.
//
// Round-4 change vs round 3 (979 us): double-buffered LDS K-loop with ONE
// barrier per K-step. Round-3 loop was sync->stage->vmcnt(0)->sync->compute:
// zero overlap between global_load_lds latency and MFMA within a block, and
// at ~2 blocks/CU there isn't enough cross-block overlap to hide it
// (MfmaUtil 30%, VALUBusy 12% -> ~58% stall). New loop:
//     stage(buf0)
//     loop: sync            (compiler's pre-barrier vmcnt(0) drains cur's stage;
//                            lgkm drain protects last iter's ds_reads)
//           stage(next buf) (flies during compute)
//           compute(cur)
// Loads get the whole compute phase (~400+ cyc) to land. LDS 32 KB/block.
// Both GEMMs: __launch_bounds__(256,3).
//
// Buffer plan (harness restores d_in before every launch):
//   cvt#1: x -> d_out lo (xb), Wq -> d_out hi (wqb)
//   cvt#2: Wk -> Wq-buf lo (wkb), Wv -> Wq-buf hi (wvb)   [Wq consumed]
//   qkv  : q -> Wk-buf lo (bf16), k -> Wk-buf hi (bf16), v -> Wv-buf (fp32)
//   S    : q@k.T/64 -> d_out (fp32), then softmax*v in place.
//
// Fragment layouts per learn_hip m89/m91:
//   A frag:  A[m = lane&15][k = (lane>>4)*8 + j]
//   B frag (B^T): B[n = lane&15][k = (lane>>4)*8 + j]
//   C/D: col = lane&15, row = (lane>>4)*4 + reg

#define NDIM 4096

typedef __bf16 bf16x8 __attribute__((ext_vector_type(8)));
typedef float f32x4 __attribute__((ext_vector_type(4)));
typedef unsigned short us8 __attribute__((ext_vector_type(8)));

__device__ __forceinline__ unsigned short f2bf(float f) {
  unsigned int u = __float_as_uint(f);
  return (unsigned short)((u + 0x7fffu + ((u >> 16) & 1u)) >> 16);  // RNE
}

__device__ __forceinline__ void async_copy16(void* lds, const void* g) {
  __builtin_amdgcn_global_load_lds(
      (__attribute__((address_space(1))) void*)(uintptr_t)g,
      (__attribute__((address_space(3))) void*)lds,
      16, 0, 0);
}

// two fp32->bf16 converts in one dispatch (blockIdx.y picks the pair)
__global__ __launch_bounds__(256) void cvt2_f32_to_bf16(
    const float* __restrict__ s0, unsigned short* __restrict__ d0,
    const float* __restrict__ s1, unsigned short* __restrict__ d1) {
  const float* src = blockIdx.y ? s1 : s0;
  unsigned short* dst = blockIdx.y ? d1 : d0;
  const int i = blockIdx.x * 256 + threadIdx.x;  // 8 floats per thread
  const float4* s = (const float4*)src;
  float4 a = s[2 * i];
  float4 b = s[2 * i + 1];
  us8 o;
  o[0] = f2bf(a.x); o[1] = f2bf(a.y); o[2] = f2bf(a.z); o[3] = f2bf(a.w);
  o[4] = f2bf(b.x); o[5] = f2bf(b.y); o[6] = f2bf(b.z); o[7] = f2bf(b.w);
  ((us8*)dst)[i] = o;
}

// ---- K-loop building blocks ----------------------------------------------
__device__ __forceinline__ void stage_tile(
    const unsigned short* __restrict__ Ag, const unsigned short* __restrict__ Bg,
    unsigned short* As0, unsigned short* Bs0, int k0) {
  async_copy16(As0,        Ag + k0);
  async_copy16(As0 + 2048, Ag + (size_t)64 * NDIM + k0);  // +64 rows
  async_copy16(Bs0,        Bg + k0);
  async_copy16(Bs0 + 2048, Bg + (size_t)64 * NDIM + k0);
}

__device__ __forceinline__ void compute_tile(
    const unsigned short* __restrict__ As, const unsigned short* __restrict__ Bs,
    int wm, int wn, int quad, int l16, f32x4 acc[4][4]) {
  bf16x8 af[4], bfr[4];
#pragma unroll
  for (int i = 0; i < 4; ++i)
    af[i] = *(const bf16x8*)&As[(wm * 64 + i * 16 + l16) * 32 + quad * 8];
#pragma unroll
  for (int j = 0; j < 4; ++j)
    bfr[j] = *(const bf16x8*)&Bs[(wn * 64 + j * 16 + l16) * 32 + quad * 8];
#pragma unroll
  for (int i = 0; i < 4; ++i)
#pragma unroll
    for (int j = 0; j < 4; ++j)
      acc[i][j] = __builtin_amdgcn_mfma_f32_16x16x32_bf16(af[i], bfr[j],
                                                          acc[i][j], 0, 0, 0);
}

// ---- shared GEMM core: double-buffered, 1 barrier / K-step ----------------
__device__ __forceinline__ void gemm_core(
    const unsigned short* __restrict__ A, const unsigned short* __restrict__ B,
    int bm, int bn, int t, unsigned short* As /*[2][4096]*/,
    unsigned short* Bs /*[2][4096]*/, f32x4 acc[4][4]) {
  const int wave = t >> 6, lane = t & 63;
  const int wm = wave >> 1, wn = wave & 1;
  const int quad = lane >> 4, l16 = lane & 15;

  const unsigned short* Ag = A + (size_t)(bm * 128 + (t >> 2)) * NDIM + (t & 3) * 8;
  const unsigned short* Bg = B + (size_t)(bn * 128 + (t >> 2)) * NDIM + (t & 3) * 8;
  unsigned short* A0 = As + t * 8;          // buf0 dest for this thread
  unsigned short* B0 = Bs + t * 8;
  unsigned short* A1 = A0 + 4096;           // buf1 = +8 KB
  unsigned short* B1 = B0 + 4096;

  stage_tile(Ag, Bg, A0, B0, 0);

  for (int k0 = 0; k0 < NDIM; k0 += 64) {
    __syncthreads();                        // drains buf0 stage; protects buf1 reads
    if (k0 + 32 < NDIM) stage_tile(Ag, Bg, A1, B1, k0 + 32);
    compute_tile(As, Bs, wm, wn, quad, l16, acc);          // buf0 @ k0

    __syncthreads();                        // drains buf1 stage; protects buf0 reads
    if (k0 + 64 < NDIM) stage_tile(Ag, Bg, A0, B0, k0 + 64);
    compute_tile(As + 4096, Bs + 4096, wm, wn, quad, l16, acc);  // buf1 @ k0+32
  }
}

// ---- fused q/k/v projection GEMM: grid (32,32,3) --------------------------
// z=0: q=x@Wq.T+bq -> bf16 ; z=1: k -> bf16 ; z=2: v -> fp32
__global__ __launch_bounds__(256, 3) void gemm_qkv(
    const unsigned short* __restrict__ A,
    const unsigned short* __restrict__ B0,
    const unsigned short* __restrict__ B1,
    const unsigned short* __restrict__ B2,
    const float* __restrict__ bias0, const float* __restrict__ bias1,
    const float* __restrict__ bias2,
    unsigned short* __restrict__ qo, unsigned short* __restrict__ ko,
    float* __restrict__ vo) {
  __shared__ __align__(16) unsigned short As[2 * 128 * 32];  // 16 KB
  __shared__ __align__(16) unsigned short Bs[2 * 128 * 32];  // 16 KB

  const int t = threadIdx.x;
  const int bm = blockIdx.y, bn = blockIdx.x, z = blockIdx.z;
  const unsigned short* B = (z == 0) ? B0 : (z == 1) ? B1 : B2;
  const float* bias = (z == 0) ? bias0 : (z == 1) ? bias1 : bias2;

  const f32x4 zero = {0.f, 0.f, 0.f, 0.f};
  f32x4 acc[4][4];
#pragma unroll
  for (int i = 0; i < 4; ++i)
#pragma unroll
    for (int j = 0; j < 4; ++j) acc[i][j] = zero;

  gemm_core(A, B, bm, bn, t, As, Bs, acc);

  const int wave = t >> 6, lane = t & 63;
  const int wm = wave >> 1, wn = wave & 1;
  const int quad = lane >> 4, l16 = lane & 15;
  unsigned short* ob = (z == 1) ? ko : qo;  // bf16 dest for z=0/1
#pragma unroll
  for (int j = 0; j < 4; ++j) {
    const int col = bn * 128 + wn * 64 + j * 16 + l16;
    const float bb = bias[col];
#pragma unroll
    for (int i = 0; i < 4; ++i) {
      const int row0 = bm * 128 + wm * 64 + i * 16 + quad * 4;
#pragma unroll
      for (int r = 0; r < 4; ++r) {
        const size_t idx = (size_t)(row0 + r) * NDIM + col;
        const float val = acc[i][j][r] + bb;
        if (z == 2) vo[idx] = val;
        else        ob[idx] = f2bf(val);
      }
    }
  }
}

// ---- S = scale * q@k.T (fp32 out) -----------------------------------------
__global__ __launch_bounds__(256, 3) void gemm_s(
    const unsigned short* __restrict__ A, const unsigned short* __restrict__ B,
    float* __restrict__ C, float scale) {
  __shared__ __align__(16) unsigned short As[2 * 128 * 32];
  __shared__ __align__(16) unsigned short Bs[2 * 128 * 32];

  const int t = threadIdx.x;
  const int bm = blockIdx.y, bn = blockIdx.x;

  const f32x4 zero = {0.f, 0.f, 0.f, 0.f};
  f32x4 acc[4][4];
#pragma unroll
  for (int i = 0; i < 4; ++i)
#pragma unroll
    for (int j = 0; j < 4; ++j) acc[i][j] = zero;

  gemm_core(A, B, bm, bn, t, As, Bs, acc);

  const int wave = t >> 6, lane = t & 63;
  const int wm = wave >> 1, wn = wave & 1;
  const int quad = lane >> 4, l16 = lane & 15;
#pragma unroll
  for (int j = 0; j < 4; ++j) {
    const int col = bn * 128 + wn * 64 + j * 16 + l16;
#pragma unroll
    for (int i = 0; i < 4; ++i) {
      const int row0 = bm * 128 + wm * 64 + i * 16 + quad * 4;
#pragma unroll
      for (int r = 0; r < 4; ++r)
        C[(size_t)(row0 + r) * NDIM + col] = acc[i][j][r] * scale;
    }
  }
}

// one block per row: out[row][:] = softmax(S[row][:]) * V[row][:]  (in-place ok)
__global__ __launch_bounds__(256) void softmax_mul(
    const float* __restrict__ S, const float* __restrict__ V,
    float* __restrict__ out) {
  const int row = blockIdx.x;
  const int t = threadIdx.x;
  const int lane = t & 63, wave = t >> 6;
  const float4* Sr = (const float4*)(S + (size_t)row * NDIM);
  const float4* Vr = (const float4*)(V + (size_t)row * NDIM);
  float4* Or = (float4*)(out + (size_t)row * NDIM);

  float4 p[4];
  float m = -3.4e38f;
#pragma unroll
  for (int c = 0; c < 4; ++c) {
    p[c] = Sr[t + 256 * c];
    m = fmaxf(m, fmaxf(fmaxf(p[c].x, p[c].y), fmaxf(p[c].z, p[c].w)));
  }
#pragma unroll
  for (int off = 32; off > 0; off >>= 1) m = fmaxf(m, __shfl_xor(m, off));
  __shared__ float redm[4], reds[4];
  if (lane == 0) redm[wave] = m;
  __syncthreads();
  m = fmaxf(fmaxf(redm[0], redm[1]), fmaxf(redm[2], redm[3]));

  float s = 0.f;
#pragma unroll
  for (int c = 0; c < 4; ++c) {
    p[c].x = __expf(p[c].x - m);
    p[c].y = __expf(p[c].y - m);
    p[c].z = __expf(p[c].z - m);
    p[c].w = __expf(p[c].w - m);
    s += (p[c].x + p[c].y) + (p[c].z + p[c].w);
  }
#pragma unroll
  for (int off = 32; off > 0; off >>= 1) s += __shfl_xor(s, off);
  if (lane == 0) reds[wave] = s;
  __syncthreads();
  s = (reds[0] + reds[1]) + (reds[2] + reds[3]);
  const float inv = 1.0f / s;

#pragma unroll
  for (int c = 0; c < 4; ++c) {
    float4 vv = Vr[t + 256 * c];
    float4 o;
    o.x = p[c].x * inv * vv.x;
    o.y = p[c].y * inv * vv.y;
    o.z = p[c].z * inv * vv.z;
    o.w = p[c].w * inv * vv.w;
    Or[t + 256 * c] = o;
  }
}

extern "C" void kernel_launch(void* const* d_in, const int* in_sizes, int n_in,
                              void* d_out, int out_size, void* d_ws, size_t ws_size,
                              hipStream_t stream) {
  const float* x  = (const float*)d_in[0];
  const float* Wq = (const float*)d_in[1];
  const float* bq = (const float*)d_in[2];
  const float* Wk = (const float*)d_in[3];
  const float* bk = (const float*)d_in[4];
  const float* Wv = (const float*)d_in[5];
  const float* bv = (const float*)d_in[6];
  float* out = (float*)d_out;

  const size_t NN = (size_t)NDIM * NDIM;

  unsigned short* xb  = (unsigned short*)d_out;   // x  bf16 (d_out lo)
  unsigned short* wqb = xb + NN;                  // Wq bf16 (d_out hi)
  unsigned short* wkb = (unsigned short*)d_in[1]; // Wk bf16 (Wq-buf lo)
  unsigned short* wvb = wkb + NN;                 // Wv bf16 (Wq-buf hi)
  unsigned short* qb  = (unsigned short*)d_in[3]; // q  bf16 (Wk-buf lo)
  unsigned short* kb  = qb + NN;                  // k  bf16 (Wk-buf hi)
  float*          vf  = (float*)d_in[5];          // v  fp32 (Wv-buf)
  float*          Sf  = (float*)d_out;            // S  fp32 (xb/wqb dead)

  const int cvtBlocks = (int)(NN / (256 * 8));    // 8192

  cvt2_f32_to_bf16<<<dim3(cvtBlocks, 2), 256, 0, stream>>>(x, xb, Wq, wqb);
  cvt2_f32_to_bf16<<<dim3(cvtBlocks, 2), 256, 0, stream>>>(Wk, wkb, Wv, wvb);

  gemm_qkv<<<dim3(32, 32, 3), 256, 0, stream>>>(xb, wqb, wkb, wvb,
                                                bq, bk, bv, qb, kb, vf);

  gemm_s<<<dim3(32, 32), 256, 0, stream>>>(qb, kb, Sf, 0.015625f);

  softmax_mul<<<NDIM, 256, 0, stream>>>(Sf, vf, out);
}